// Round 6
// baseline (1890.938 us; speedup 1.0000x reference)
//
#include <hip/hip_runtime.h>

// ODE-GRU recurrence, B=128, L=2048, I=D=64.
// One block per batch, 512 threads (8 waves, 2/SIMD).
// R6: uniform octet layout. Element e owned by lanes 8e..8e+7; lane holds
// K-chunk [8c,8c+8) (c = tid&7) of ALL 8 dot-rows of e:
//   Round 1 (read h):  u=dw1_e@h, G0=Whh_e@h, G1=Whh_{64+e}@h, G2=Whh_{128+e}@h
//   Round 2 (read t1): m0=M2_e@t1, m1=M2_{64+e}@t1, m2=M2_{128+e}@t1, hot=dw2_e@t1
// 8-lane DPP butterfly (xor1,xor2,half-mirror) -> every lane has all sums;
// gate tail computed redundantly by all 8 lanes (NO divergence, no swap);
// lane c==0 writes. 2 barriers/step. gx stored as [ts][3e+r] (conflict-free
// broadcast). Carried: gh linearity (M2=Whh@dw2, c2=Whh@db2 in d_ws),
// packed-fp32 dots, gx tile precompute, LDS-buffered output flush.

#define NB    128
#define SEQ   2048
#define DIM   64
#define TILE  32
#define XS    68     // sh_x row stride (floats)
#define G3    196    // sh_gx3 row stride (floats; 192 + pad)

typedef float f32x2 __attribute__((ext_vector_type(2)));

__device__ __forceinline__ float fast_rcp(float x) { return __builtin_amdgcn_rcpf(x); }

__device__ __forceinline__ float sigmoid_f(float v) {
    return fast_rcp(1.0f + __expf(-v));
}
__device__ __forceinline__ float tanh_f(float v) {
    float e = __expf(2.0f * v);
    return fmaf(-2.0f, fast_rcp(e + 1.0f), 1.0f);
}

// 8-lane butterfly: xor1 (quad_perm 0xB1), xor2 (0x4E), xor4 (row_half_mirror).
// Every lane of the octet ends with the full 8-chunk sum.
__device__ __forceinline__ float red8(float v) {
    v += __int_as_float(__builtin_amdgcn_mov_dpp(__float_as_int(v), 0xB1,  0xF, 0xF, true));
    v += __int_as_float(__builtin_amdgcn_mov_dpp(__float_as_int(v), 0x4E,  0xF, 0xF, true));
    v += __int_as_float(__builtin_amdgcn_mov_dpp(__float_as_int(v), 0x141, 0xF, 0xF, true));
    return v;
}

// 8-element dot (2 float4 each side): 4 v_pk_fma_f32 + pk_add + add.
__device__ __forceinline__ float dot8p(const float4* w, const float4* v) {
    f32x2 a; a.x = 0.f; a.y = 0.f;
    f32x2 b; b.x = 0.f; b.y = 0.f;
    f32x2 w0l; w0l.x = w[0].x; w0l.y = w[0].y;
    f32x2 w0h; w0h.x = w[0].z; w0h.y = w[0].w;
    f32x2 w1l; w1l.x = w[1].x; w1l.y = w[1].y;
    f32x2 w1h; w1h.x = w[1].z; w1h.y = w[1].w;
    f32x2 v0l; v0l.x = v[0].x; v0l.y = v[0].y;
    f32x2 v0h; v0h.x = v[0].z; v0h.y = v[0].w;
    f32x2 v1l; v1l.x = v[1].x; v1l.y = v[1].y;
    f32x2 v1h; v1h.x = v[1].z; v1h.y = v[1].w;
    a = __builtin_elementwise_fma(w0l, v0l, a);
    b = __builtin_elementwise_fma(w0h, v0h, b);
    a = __builtin_elementwise_fma(w1l, v1l, a);
    b = __builtin_elementwise_fma(w1h, v1h, b);
    f32x2 s = a + b;
    return s.x + s.y;
}

// ---- prep: M2 = Whh @ dw2 (192x64), c2 = Whh @ db2 (192) ----
__global__ void odegru_prep(const float* __restrict__ w_hh,
                            const float* __restrict__ dw2,
                            const float* __restrict__ db2,
                            float* __restrict__ m2,   // 192*64
                            float* __restrict__ c2)   // 192
{
    const int idx = blockIdx.x * 256 + threadIdx.x;
    if (idx < 192 * 64) {
        const int r = idx >> 6, k = idx & 63;
        float s = 0.f;
#pragma unroll
        for (int j = 0; j < 64; j++) s = fmaf(w_hh[r * 64 + j], dw2[j * 64 + k], s);
        m2[idx] = s;
    }
    if (idx < 192) {
        float s = 0.f;
#pragma unroll
        for (int j = 0; j < 64; j++) s = fmaf(w_hh[idx * 64 + j], db2[j], s);
        c2[idx] = s;
    }
}

__global__ __launch_bounds__(512, 2)
void odegru_fused(const float* __restrict__ x,        // (B,L,I)
                  const float* __restrict__ tds,      // (B,L)
                  const int*   __restrict__ seq_lens, // (B)
                  const float* __restrict__ h0,       // (D)
                  const float* __restrict__ w_ih,     // (3D,I)
                  const float* __restrict__ w_hh,     // (3D,D)
                  const float* __restrict__ b_ih,     // (3D)
                  const float* __restrict__ b_hh,     // (3D)
                  const float* __restrict__ dw1,      // (D,D)
                  const float* __restrict__ db1,      // (D)
                  const float* __restrict__ dw2,      // (D,D)
                  const float* __restrict__ db2,      // (D)
                  const float* __restrict__ m2,       // (3D,D) = Whh@dw2
                  const float* __restrict__ c2,       // (3D)   = Whh@db2
                  float* __restrict__ out)            // (B,L,D) ++ (B,D)
{
    const int b   = blockIdx.x;
    const int tid = threadIdx.x;
    const int e   = tid >> 3;         // octet = element 0..63
    const int c   = tid & 7;          // K-chunk [8c, 8c+8)
    const int seqlen = seq_lens[b];

    __shared__ float sh_h [DIM];
    __shared__ float sh_t1[DIM];
    __shared__ float sh_x [TILE][XS];
    __shared__ float sh_gx[TILE][G3];   // [ts][3e + r]
    __shared__ float sh_dt[TILE];
    __shared__ float sh_out[TILE][DIM];

    // ---- persistent weights: 8 dot-rows x 8 floats + 3 gx-rows x 8 = 88 fl ----
    float4 wu[2], wg0[2], wg1[2], wg2[2], wm0[2], wm1[2], wm2[2], wd[2];
    float4 wi0[2], wi1[2], wi2[2];
    {
        const float4* dw1v = (const float4*)dw1;
        const float4* dw2v = (const float4*)dw2;
        const float4* whhv = (const float4*)w_hh;
        const float4* m2v  = (const float4*)m2;
        const float4* wihv = (const float4*)w_ih;
        const int f = 2 * c;   // float4 offset of this chunk within a 16-f4 row
#pragma unroll
        for (int i = 0; i < 2; i++) {
            wu [i] = dw1v[e * 16 + f + i];
            wg0[i] = whhv[(e)       * 16 + f + i];
            wg1[i] = whhv[(64 + e)  * 16 + f + i];
            wg2[i] = whhv[(128 + e) * 16 + f + i];
            wm0[i] = m2v [(e)       * 16 + f + i];
            wm1[i] = m2v [(64 + e)  * 16 + f + i];
            wm2[i] = m2v [(128 + e) * 16 + f + i];
            wd [i] = dw2v[e * 16 + f + i];
            wi0[i] = wihv[(e)       * 16 + f + i];
            wi1[i] = wihv[(64 + e)  * 16 + f + i];
            wi2[i] = wihv[(128 + e) * 16 + f + i];
        }
    }
    // biases (per element, replicated across octet lanes)
    const float kdb1 = db1[e], kdb2 = db2[e];
    const float kbh0 = b_hh[e], kbh1 = b_hh[64 + e], kbh2 = b_hh[128 + e];
    const float kc0  = c2[e],   kc1  = c2[64 + e],   kc2  = c2[128 + e];
    const float kbx0 = b_ih[e], kbx1 = b_ih[64 + e], kbx2 = b_ih[128 + e];

    if (tid < DIM) sh_h[tid] = h0[tid];

    const float* xb  = x   + (size_t)b * SEQ * DIM;
    const float* tdb = tds + (size_t)b * SEQ;
    float* outb = out + (size_t)b * SEQ * DIM;
    float* finb = out + (size_t)NB * SEQ * DIM + (size_t)b * DIM;

    for (int t0 = 0; t0 < SEQ; t0 += TILE) {
        // ---- stage x tile (masked) + dt tile (masked); 512 f4 = 1/thread ----
        {
            const float4* src = (const float4*)(xb + (size_t)t0 * DIM);
            const int ts0 = tid >> 4, j = tid & 15;
            float4 v = src[tid];
            if (t0 + ts0 >= seqlen) v = make_float4(0.f, 0.f, 0.f, 0.f);
            *(float4*)&sh_x[ts0][4 * j] = v;
            if (tid < TILE) {
                const int t = t0 + tid;
                sh_dt[tid] = (t < seqlen) ? tdb[t] : 0.0f;
            }
        }
        __syncthreads();

        // ---- gx tile: octet e computes rows {e,64+e,128+e} for all ts ----
        {
#pragma unroll 4
            for (int ts = 0; ts < TILE; ts++) {
                const float4* xv = (const float4*)&sh_x[ts][0];
                float4 x4[2] = { xv[2 * c], xv[2 * c + 1] };
                const float A0 = red8(dot8p(wi0, x4));
                const float A1 = red8(dot8p(wi1, x4));
                const float A2 = red8(dot8p(wi2, x4));
                if (c == 0) {
                    sh_gx[ts][3 * e]     = A0 + kbx0;
                    sh_gx[ts][3 * e + 1] = A1 + kbx1;
                    sh_gx[ts][3 * e + 2] = A2 + kbx2;
                }
            }
        }
        __syncthreads();

#pragma unroll 1
        for (int ts = 0; ts < TILE; ts++) {
            const int t = t0 + ts;

            // ---- prefetch (broadcast LDS reads, conflict-free) ----
            const float dtv = sh_dt[ts];
            const float gxr = sh_gx[ts][3 * e];
            const float gxz = sh_gx[ts][3 * e + 1];
            const float gxn = sh_gx[ts][3 * e + 2];
            const float hq  = sh_h[e];

            // ---- Round 1 (read h chunk): 4 dots of 8 ----
            {
                const float4* hv = (const float4*)sh_h;
                float4 h4[2] = { hv[2 * c], hv[2 * c + 1] };
                const float u  = red8(dot8p(wu, h4));
                if (c == 0) sh_t1[e] = tanh_f(u + kdb1);
            }
            // G0..G2 also depend on h — compute before the barrier
            float G0, G1, G2;
            {
                const float4* hv = (const float4*)sh_h;
                float4 h4[2] = { hv[2 * c], hv[2 * c + 1] };
                G0 = red8(dot8p(wg0, h4));
                G1 = red8(dot8p(wg1, h4));
                G2 = red8(dot8p(wg2, h4));
            }
            __syncthreads();   // t1 visible

            // ---- Round 2 (read t1 chunk): 4 dots + full tail, all lanes ----
            {
                const float4* tv = (const float4*)sh_t1;
                float4 t4[2] = { tv[2 * c], tv[2 * c + 1] };
                const float m0  = red8(dot8p(wm0, t4));
                const float m1  = red8(dot8p(wm1, t4));
                const float m2s = red8(dot8p(wm2, t4));
                const float hot = red8(dot8p(wd,  t4));
                const float r   = sigmoid_f(gxr + G0 + fmaf(dtv, m0  + kc0, kbh0));
                const float z   = sigmoid_f(gxz + G1 + fmaf(dtv, m1  + kc1, kbh1));
                const float ghn =           G2 + fmaf(dtv, m2s + kc2, kbh2);
                const float ho  = fmaf(dtv, hot + kdb2, hq);
                const float n   = tanh_f(fmaf(r, ghn, gxn));
                const float hn  = fmaf(z, ho - n, n);   // (1-z)*n + z*ho
                if (c == 0) {
                    sh_h[e] = hn;
                    sh_out[ts][e] = hn;
                    if (t == seqlen - 1) finb[e] = hn;
                }
            }
            __syncthreads();   // h visible
        }

        // ---- flush output tile: 512 float4 = 1/thread ----
        {
            float4* dst = (float4*)(outb + (size_t)t0 * DIM);
            const float4* srcv = (const float4*)(&sh_out[0][0]);
            dst[tid] = srcv[tid];
        }
    }
}

extern "C" void kernel_launch(void* const* d_in, const int* in_sizes, int n_in,
                              void* d_out, int out_size, void* d_ws, size_t ws_size,
                              hipStream_t stream) {
    const float* x    = (const float*)d_in[0];
    const float* tds  = (const float*)d_in[1];
    const int*   sl   = (const int*)  d_in[2];
    const float* h0   = (const float*)d_in[3];
    const float* w_ih = (const float*)d_in[4];
    const float* w_hh = (const float*)d_in[5];
    const float* b_ih = (const float*)d_in[6];
    const float* b_hh = (const float*)d_in[7];
    const float* dw1  = (const float*)d_in[8];
    const float* db1  = (const float*)d_in[9];
    const float* dw2  = (const float*)d_in[10];
    const float* db2  = (const float*)d_in[11];
    float* out = (float*)d_out;

    float* m2 = (float*)d_ws;              // 192*64 floats
    float* c2 = m2 + 192 * 64;             // 192 floats

    odegru_prep<<<dim3(48), dim3(256), 0, stream>>>(w_hh, dw2, db2, m2, c2);
    odegru_fused<<<dim3(NB), dim3(512), 0, stream>>>(
        x, tds, sl, h0, w_ih, w_hh, b_ih, b_hh, dw1, db1, dw2, db2, m2, c2, out);
}